// Round 11
// baseline (365.346 us; speedup 1.0000x reference)
//
#include <hip/hip_runtime.h>
#include <hip/hip_bf16.h>
#include <cstdint>
#include <math.h>

// Problem dims
#define BB 8
#define TT 1024
#define CC 768
#define HH 12
#define MROWS (BB*TT)   // 8192

typedef __hip_bfloat16 bf16;
typedef __attribute__((ext_vector_type(8))) __bf16 bf16x8;
typedef __attribute__((ext_vector_type(4))) float f32x4;

#define MFMA16(a,b,c) __builtin_amdgcn_mfma_f32_16x16x32_bf16(a,b,c,0,0,0)

// lgkm-only barrier: legal when the only outstanding vmem ops at the
// barrier are private register loads (not observable cross-thread). Avoids
// the compiler's s_waitcnt vmcnt(0) drain at __syncthreads.
__device__ __forceinline__ void lds_barrier() {
  asm volatile("s_waitcnt lgkmcnt(0)\n\ts_barrier" ::: "memory");
}

// ---------------- LayerNorm: f32 [rows][768] -> bf16 ----------------
__global__ __launch_bounds__(256) void ln_kernel(
    const float* __restrict__ x, const float* __restrict__ scale,
    const float* __restrict__ bias, bf16* __restrict__ out)
{
  int row = blockIdx.x;
  const float* xr = x + (size_t)row * CC;
  float v[3];
  float s = 0.f, s2 = 0.f;
  for (int i = 0; i < 3; i++) {
    v[i] = xr[threadIdx.x + i*256];
    s += v[i]; s2 += v[i]*v[i];
  }
  for (int m = 1; m < 64; m <<= 1) { s += __shfl_xor(s, m); s2 += __shfl_xor(s2, m); }
  __shared__ float ssum[4], ssum2[4];
  int w = threadIdx.x >> 6;
  if ((threadIdx.x & 63) == 0) { ssum[w] = s; ssum2[w] = s2; }
  __syncthreads();
  s = ssum[0]+ssum[1]+ssum[2]+ssum[3];
  s2 = ssum2[0]+ssum2[1]+ssum2[2]+ssum2[3];
  float mu = s * (1.f/CC);
  float var = s2 * (1.f/CC) - mu*mu;
  float rs = rsqrtf(var + 1e-5f);
  bf16* orow = out + (size_t)row * CC;
  for (int i = 0; i < 3; i++) {
    int c = threadIdx.x + i*256;
    orow[c] = __float2bfloat16((v[i]-mu)*rs*scale[c] + bias[c]);
  }
}

// ------------- merged weight transpose-cast: 4 weights in one launch -------------
__global__ __launch_bounds__(256) void wtrans_all(
    const float* __restrict__ s0, const float* __restrict__ s1,
    const float* __restrict__ s2, const float* __restrict__ s3,
    bf16* __restrict__ d0, bf16* __restrict__ d1,
    bf16* __restrict__ d2, bf16* __restrict__ d3)
{
  int bid = blockIdx.x;
  const float* src; bf16* dst; int K, N, r;
  if (bid < 1728)      { src = s0; dst = d0; K = 768;  N = 2304; r = bid; }
  else if (bid < 2304) { src = s1; dst = d1; K = 768;  N = 768;  r = bid - 1728; }
  else if (bid < 4608) { src = s2; dst = d2; K = 768;  N = 3072; r = bid - 2304; }
  else                 { src = s3; dst = d3; K = 3072; N = 768;  r = bid - 4608; }
  int nbx = N >> 5;
  int bx = r % nbx, by = r / nbx;
  __shared__ float tile[32][33];
  int n0 = bx * 32, k0 = by * 32;
  int tx = threadIdx.x & 31, ty = threadIdx.x >> 5;   // ty 0..7
  for (int i = 0; i < 4; i++)
    tile[ty + i*8][tx] = src[(size_t)(k0 + ty + i*8)*N + n0 + tx];
  __syncthreads();
  for (int i = 0; i < 4; i++)
    dst[(size_t)(n0 + ty + i*8)*K + k0 + tx] = __float2bfloat16(tile[tx][ty + i*8]);
}

// ------------- V transpose: [BH][T][64] -> [BH][64][T] (bf16) -------------
__global__ __launch_bounds__(256) void vtrans_kernel(
    const bf16* __restrict__ src, bf16* __restrict__ dst)
{
  __shared__ bf16 tile[64][65];
  int bh = blockIdx.x >> 4, t0 = (blockIdx.x & 15) * 64;
  const bf16* s = src + ((size_t)bh * TT + t0) * 64;
  for (int i = 0; i < 16; i++) {
    int idx = threadIdx.x + i*256;
    tile[idx >> 6][idx & 63] = s[idx];
  }
  __syncthreads();
  bf16* o = dst + (size_t)bh * 64 * TT + t0;
  for (int i = 0; i < 16; i++) {
    int idx = threadIdx.x + i*256;
    int d = idx >> 6, t = idx & 63;
    o[(size_t)d * TT + t] = tile[t][d];
  }
}

// ------------- 128x128 GEMM, BK=64: C[M,N] = A_bf16[M,K] * Bt_bf16[N,K]^T + bias ---
// BK 32->64 halves barrier count (32 MFMA per barrier vs 16). LDS 64 KiB but
// we're register-bound at 2 blocks/CU either way, so no occupancy cost (the
// m132 BK=128 failure mode doesn't apply). 1-deep reg prefetch: the 32-MFMA
// compute phase (~600+cy) covers HBM latency, matching r9's 2-deep distance.
// 64-col rows are 128B stride (all rows bank 0) -> XOR swizzle slot^=(row&7)
// on BOTH write and read; enumeration gives uniform 8 lanes/slot = b128 minimum.
template<int EPI>
__global__ __launch_bounds__(256) void gemm_bt(
    const bf16* __restrict__ A, const bf16* __restrict__ Bt,
    const float* __restrict__ bias, int Mdim, int Ndim, int Kdim,
    const float* __restrict__ res, void* __restrict__ out0,
    bf16* __restrict__ outK, bf16* __restrict__ outV)
{
  __shared__ bf16 As[2][128*64];   // 32 KiB
  __shared__ bf16 Bs[2][128*64];   // 32 KiB
  int tid = threadIdx.x;
  int wave = tid >> 6, lane = tid & 63;
  int quad = lane >> 4, l15 = lane & 15;
  int wr = wave >> 1, wc = wave & 1;

  int Nb = gridDim.x;
  int lin = blockIdx.y * Nb + blockIdx.x;
  int band = lin / (8*Nb);
  int rem  = lin - band*8*Nb;
  int m0 = (band*8 + (rem & 7)) * 128;
  int n0 = (rem >> 3) * 128;

  const int srow = lane >> 2;          // 0..15
  const int scol = (lane & 3) * 8;     // first 16B slot (bf16 elems)

  f32x4 acc[4][4];
  for (int i = 0; i < 4; i++) for (int j = 0; j < 4; j++)
    acc[i][j] = (f32x4){0.f,0.f,0.f,0.f};

  // staging: seg0 = rows wave*16..+15, seg1 = rows 64+wave*16..+15; two 16B
  // slots per lane per row-segment: scol and scol+32.
  const bf16* pa0 = A  + (size_t)(m0 + wave*16      + srow)*Kdim + scol;
  const bf16* pa1 = A  + (size_t)(m0 + 64 + wave*16 + srow)*Kdim + scol;
  const bf16* pb0 = Bt + (size_t)(n0 + wave*16      + srow)*Kdim + scol;
  const bf16* pb1 = Bt + (size_t)(n0 + 64 + wave*16 + srow)*Kdim + scol;

  // LDS write: row_local = wave*16+srow (seg0) / +64 (seg1); slot' = slot^(row&7).
  const int xr = srow & 7;
  const int woff = (wave*16 + srow)*64 + ((lane & 3) ^ xr)*8;  // seg0, slot0
  // slot1 (= slot0 + 4 pre-swizzle) lives at woff ^ 32; seg1 at +4096.

  // fragment read swizzle: row = base + l15 (base mult of 16), k-half kh,
  // slot = (kh*4 + quad) ^ (l15 & 7); kh=1 is ^32 on the byte offset.
  const int rsw = (quad ^ (l15 & 7)) * 8;

  const int niter = Kdim >> 6;     // 12 or 48

  bf16x8 ra0, ra1, ra2, ra3, rb0, rb1, rb2, rb3;

#define LOADSET() do { \
    ra0 = *reinterpret_cast<const bf16x8*>(pa0); \
    ra1 = *reinterpret_cast<const bf16x8*>(pa0 + 32); \
    ra2 = *reinterpret_cast<const bf16x8*>(pa1); \
    ra3 = *reinterpret_cast<const bf16x8*>(pa1 + 32); \
    rb0 = *reinterpret_cast<const bf16x8*>(pb0); \
    rb1 = *reinterpret_cast<const bf16x8*>(pb0 + 32); \
    rb2 = *reinterpret_cast<const bf16x8*>(pb1); \
    rb3 = *reinterpret_cast<const bf16x8*>(pb1 + 32); \
    pa0 += 64; pa1 += 64; pb0 += 64; pb1 += 64; } while(0)

#define WRITESET(buf) do { \
    *reinterpret_cast<bf16x8*>(As[buf] + woff)          = ra0; \
    *reinterpret_cast<bf16x8*>(As[buf] + (woff ^ 32))   = ra1; \
    *reinterpret_cast<bf16x8*>(As[buf] + 4096 + woff)        = ra2; \
    *reinterpret_cast<bf16x8*>(As[buf] + 4096 + (woff ^ 32)) = ra3; \
    *reinterpret_cast<bf16x8*>(Bs[buf] + woff)          = rb0; \
    *reinterpret_cast<bf16x8*>(Bs[buf] + (woff ^ 32))   = rb1; \
    *reinterpret_cast<bf16x8*>(Bs[buf] + 4096 + woff)        = rb2; \
    *reinterpret_cast<bf16x8*>(Bs[buf] + 4096 + (woff ^ 32)) = rb3; } while(0)

#define COMPUTE(buf) do { \
    _Pragma("unroll") \
    for (int kh = 0; kh < 2; kh++) { \
      const int ks = kh * 32; \
      bf16x8 bfr[4]; \
      _Pragma("unroll") \
      for (int j = 0; j < 4; j++) \
        bfr[j] = *reinterpret_cast<const bf16x8*>(Bs[buf] + (wc*64 + j*16 + l15)*64 + (rsw ^ ks)); \
      _Pragma("unroll") \
      for (int i = 0; i < 4; i++) { \
        bf16x8 af = *reinterpret_cast<const bf16x8*>(As[buf] + (wr*64 + i*16 + l15)*64 + (rsw ^ ks)); \
        _Pragma("unroll") \
        for (int j = 0; j < 4; j++) \
          acc[i][j] = MFMA16(af, bfr[j], acc[i][j]); \
      } \
    } } while(0)

  // prologue: tile 0 -> regs -> buf 0
  LOADSET();
  WRITESET(0);
  lds_barrier();

  for (int it = 0; it < niter; it++) {
    int cur = it & 1, nxt = cur ^ 1;
    bool more = (it + 1 < niter);
    if (more) LOADSET();               // tile it+1 in flight across the phase
    COMPUTE(cur);                      // 32 MFMA
    if (more) {
      WRITESET(nxt);                   // vmcnt wait lands here, post-MFMAs
      lds_barrier();
    }
  }
#undef LOADSET
#undef WRITESET
#undef COMPUTE

  for (int i = 0; i < 4; i++) {
    for (int j = 0; j < 4; j++) {
      for (int r = 0; r < 4; r++) {
        int row = m0 + wr*64 + i*16 + quad*4 + r;
        int col = n0 + wc*64 + j*16 + l15;
        float cv = acc[i][j][r] + bias[col];
        if (EPI == 0) {
          int part = col / 768;
          int cc = col - part*768;
          int h = cc >> 6, d = cc & 63;
          int b = row >> 10, t = row & 1023;
          bf16* dst = (part == 0) ? (bf16*)out0 : (part == 1) ? outK : outV;
          dst[(((size_t)(b*HH + h))*TT + t)*64 + d] = __float2bfloat16(cv);
        } else if (EPI == 1) {
          ((float*)out0)[(size_t)row*Ndim + col] = cv + res[(size_t)row*Ndim + col];
        } else {
          float u = cv;
          float y = 0.7978845608f*(u + 0.044715f*u*u*u);
          float e = __expf(2.f*fabsf(y));
          float z = 2.f/(e + 1.f);                  // 1 - tanh(|y|)
          float sel = (y >= 0.f) ? (2.f - z) : z;   // 1 + tanh(y)
          ((bf16*)out0)[(size_t)row*Ndim + col] = __float2bfloat16(0.5f*u*sel);
        }
      }
    }
  }
}

// ------------- flash attention, QBLK=128 (round-10 incumbent) -------------
__global__ __launch_bounds__(512) void attn_kernel(
    const bf16* __restrict__ Q, const bf16* __restrict__ Kb,
    const bf16* __restrict__ Vt, bf16* __restrict__ ctx)
{
  __shared__ bf16 Ks[64*64];      // [key][d], swizzled      (8 KB)
  __shared__ bf16 Vs[64*64];      // [d][key], swizzled      (8 KB)
  __shared__ bf16 Ps[8*16*64];    // per-wave [q][key], q-swizzled (16 KB)

  int tid = threadIdx.x, wave = tid >> 6, lane = tid & 63;
  int quad = lane >> 4, l15 = lane & 15;
  int bh = blockIdx.x >> 3;
  int tile = 7 - (blockIdx.x & 7);            // heavy tiles first
  int q0b = tile*128;
  int q0w = q0b + wave*16;
  int b = bh / HH, h = bh - b*HH;
  const bf16* Qp = Q + ((size_t)bh*TT + q0w)*64;
  const bf16* Kp = Kb + (size_t)bh*TT*64;
  const bf16* Vp = Vt + (size_t)bh*64*TT;
  bf16* Pw = Ps + wave*16*64;

  bf16x8 qf[2];
  qf[0] = *reinterpret_cast<const bf16x8*>(Qp + l15*64 + quad*8);
  qf[1] = *reinterpret_cast<const bf16x8*>(Qp + l15*64 + 32 + quad*8);

  f32x4 O[4];
  for (int j = 0; j < 4; j++) O[j] = (f32x4){0.f,0.f,0.f,0.f};
  float lsum[4] = {0.f, 0.f, 0.f, 0.f};
  const float c2 = 0.18033688f;   // (1/8) * log2(e)

  // staging: 512 threads cover 64 rows x 8 slots exactly (1 K + 1 V load each)
  const int srow = tid >> 3;      // 0..63
  const int sc   = tid & 7;       // 16B block within 128B row
  const int ph   = sc ^ (srow & 7);

  int nc = 2*tile + 2;            // number of 64-key chunks (covers q0b+127)

  bf16x8 kreg, vreg, kreg2, vreg2;
  kreg = *reinterpret_cast<const bf16x8*>(Kp + (size_t)srow*64 + sc*8);
  vreg = *reinterpret_cast<const bf16x8*>(Vp + (size_t)srow*TT + sc*8);

  for (int ci = 0; ci < nc; ci++) {
    int kbase = ci*64;
    __syncthreads();
    *reinterpret_cast<bf16x8*>(Ks + srow*64 + ph*8) = kreg;
    *reinterpret_cast<bf16x8*>(Vs + srow*64 + ph*8) = vreg;
    if (ci + 1 < nc) {
      int kb2 = kbase + 64;
      kreg2 = *reinterpret_cast<const bf16x8*>(Kp + (size_t)(kb2 + srow)*64 + sc*8);
      vreg2 = *reinterpret_cast<const bf16x8*>(Vp + (size_t)srow*TT + kb2 + sc*8);
    }
    __syncthreads();

    f32x4 S[4];
    for (int j = 0; j < 4; j++) S[j] = (f32x4){0.f,0.f,0.f,0.f};
    for (int kh = 0; kh < 2; kh++) {
      for (int j = 0; j < 4; j++) {
        int key = j*16 + l15;
        bf16x8 kf = *reinterpret_cast<const bf16x8*>(
            Ks + key*64 + ((kh*4 + quad) ^ (key & 7))*8);
        S[j] = MFMA16(qf[kh], kf, S[j]);
      }
    }

    float p[4][4];
    if (kbase + 63 > q0w) {
      for (int j = 0; j < 4; j++) {
        int key = kbase + j*16 + l15;
        for (int r = 0; r < 4; r++) {
          int row = q0w + quad*4 + r;
          p[j][r] = (key <= row) ? __builtin_amdgcn_exp2f(S[j][r]*c2) : 0.f;
        }
      }
    } else {
      for (int j = 0; j < 4; j++)
        for (int r = 0; r < 4; r++)
          p[j][r] = __builtin_amdgcn_exp2f(S[j][r]*c2);
    }
    for (int j = 0; j < 4; j++)
      for (int r = 0; r < 4; r++) lsum[r] += p[j][r];

    for (int j = 0; j < 4; j++) {
      int cblk = j*2 + (l15 >> 3);
      int koff = l15 & 7;
      for (int r = 0; r < 4; r++) {
        int q = quad*4 + r;
        Pw[q*64 + (cblk ^ (q & 7))*8 + koff] = __float2bfloat16(p[j][r]);
      }
    }

    for (int kh = 0; kh < 2; kh++) {
      bf16x8 pf = *reinterpret_cast<const bf16x8*>(
          Pw + l15*64 + ((kh*4 + quad) ^ (l15 & 7))*8);
      for (int j = 0; j < 4; j++) {
        int d = j*16 + l15;
        bf16x8 vf = *reinterpret_cast<const bf16x8*>(
            Vs + d*64 + ((kh*4 + quad) ^ (d & 7))*8);
        O[j] = MFMA16(pf, vf, O[j]);
      }
    }

    kreg = kreg2; vreg = vreg2;
  }

  for (int r = 0; r < 4; r++)
    for (int msk = 1; msk < 16; msk <<= 1)
      lsum[r] += __shfl_xor(lsum[r], msk);

  bf16* cp = ctx + ((size_t)b*TT + q0w)*CC + h*64;
  for (int r = 0; r < 4; r++) {
    float inv = 1.f / lsum[r];
    int row = quad*4 + r;
    for (int j = 0; j < 4; j++)
      cp[(size_t)row*CC + j*16 + l15] = __float2bfloat16(O[j][r]*inv);
  }
}

extern "C" void kernel_launch(void* const* d_in, const int* in_sizes, int n_in,
                              void* d_out, int out_size, void* d_ws, size_t ws_size,
                              hipStream_t stream)
{
  const float* x    = (const float*)d_in[0];
  const float* ln1s = (const float*)d_in[2];
  const float* ln1b = (const float*)d_in[3];
  const float* wqkv = (const float*)d_in[4];
  const float* bqkv = (const float*)d_in[5];
  const float* wap  = (const float*)d_in[6];
  const float* bap  = (const float*)d_in[7];
  const float* ln2s = (const float*)d_in[8];
  const float* ln2b = (const float*)d_in[9];
  const float* wfc  = (const float*)d_in[10];
  const float* bfc  = (const float*)d_in[11];
  const float* wmp  = (const float*)d_in[12];
  const float* bmp  = (const float*)d_in[13];

  char* ws = (char*)d_ws;
  bf16* wqkv_t = (bf16*)ws; ws += (size_t)2304*768*2;
  bf16* wap_t  = (bf16*)ws; ws += (size_t)768*768*2;
  bf16* wfc_t  = (bf16*)ws; ws += (size_t)3072*768*2;
  bf16* wmp_t  = (bf16*)ws; ws += (size_t)768*3072*2;
  bf16* buf1   = (bf16*)ws; ws += (size_t)MROWS*CC*2;   // h / ctx / h2
  bf16* Qb     = (bf16*)ws; ws += (size_t)MROWS*CC*2;
  bf16* Kbuf   = (bf16*)ws; ws += (size_t)MROWS*CC*2;
  bf16* Vb     = (bf16*)ws; ws += (size_t)MROWS*CC*2;
  bf16* Vt     = (bf16*)ws; ws += (size_t)MROWS*CC*2;
  bf16* g      = Qb;  // reuse Q/K/V/Vt region for [8192][3072] bf16
  float* r1    = (float*)ws; ws += (size_t)MROWS*CC*4;

  dim3 blk(256);
  wtrans_all<<<6912, blk, 0, stream>>>(wqkv, wap, wfc, wmp,
                                       wqkv_t, wap_t, wfc_t, wmp_t);
  ln_kernel<<<MROWS, blk, 0, stream>>>(x, ln1s, ln1b, buf1);
  gemm_bt<0><<<dim3(2304/128, MROWS/128), blk, 0, stream>>>(
      buf1, wqkv_t, bqkv, MROWS, 2304, 768, nullptr, (void*)Qb, Kbuf, Vb);
  vtrans_kernel<<<BB*HH*16, blk, 0, stream>>>(Vb, Vt);
  attn_kernel<<<BB*HH*8, dim3(512), 0, stream>>>(Qb, Kbuf, Vt, buf1);
  gemm_bt<1><<<dim3(768/128, MROWS/128), blk, 0, stream>>>(
      buf1, wap_t, bap, MROWS, 768, 768, x, (void*)r1, nullptr, nullptr);
  ln_kernel<<<MROWS, blk, 0, stream>>>(r1, ln2s, ln2b, buf1);
  gemm_bt<2><<<dim3(3072/128, MROWS/128), blk, 0, stream>>>(
      buf1, wfc_t, bfc, MROWS, 3072, 768, nullptr, (void*)g, nullptr, nullptr);
  gemm_bt<1><<<dim3(768/128, MROWS/128), blk, 0, stream>>>(
      g, wmp_t, bmp, MROWS, 768, 3072, r1, d_out, nullptr, nullptr);
}

// Round 12
// 354.509 us; speedup vs baseline: 1.0306x; 1.0306x over previous
//
#include <hip/hip_runtime.h>
#include <hip/hip_bf16.h>
#include <cstdint>
#include <math.h>

// Problem dims
#define BB 8
#define TT 1024
#define CC 768
#define HH 12
#define MROWS (BB*TT)   // 8192

typedef __hip_bfloat16 bf16;
typedef __attribute__((ext_vector_type(8))) __bf16 bf16x8;
typedef __attribute__((ext_vector_type(4))) float f32x4;

#define MFMA16(a,b,c) __builtin_amdgcn_mfma_f32_16x16x32_bf16(a,b,c,0,0,0)

// lgkm-only barrier: legal when the only outstanding vmem ops at the
// barrier are private register loads (not observable cross-thread). Avoids
// the compiler's s_waitcnt vmcnt(0) drain at __syncthreads.
__device__ __forceinline__ void lds_barrier() {
  asm volatile("s_waitcnt lgkmcnt(0)\n\ts_barrier" ::: "memory");
}

// ---------------- LayerNorm body: f32 [rows][768] -> bf16 ----------------
__device__ __forceinline__ void ln_body(
    const float* __restrict__ x, const float* __restrict__ scale,
    const float* __restrict__ bias, bf16* __restrict__ out, int row)
{
  const float* xr = x + (size_t)row * CC;
  float v[3];
  float s = 0.f, s2 = 0.f;
  for (int i = 0; i < 3; i++) {
    v[i] = xr[threadIdx.x + i*256];
    s += v[i]; s2 += v[i]*v[i];
  }
  for (int m = 1; m < 64; m <<= 1) { s += __shfl_xor(s, m); s2 += __shfl_xor(s2, m); }
  __shared__ float ssum[4], ssum2[4];
  int w = threadIdx.x >> 6;
  if ((threadIdx.x & 63) == 0) { ssum[w] = s; ssum2[w] = s2; }
  __syncthreads();
  s = ssum[0]+ssum[1]+ssum[2]+ssum[3];
  s2 = ssum2[0]+ssum2[1]+ssum2[2]+ssum2[3];
  float mu = s * (1.f/CC);
  float var = s2 * (1.f/CC) - mu*mu;
  float rs = rsqrtf(var + 1e-5f);
  bf16* orow = out + (size_t)row * CC;
  for (int i = 0; i < 3; i++) {
    int c = threadIdx.x + i*256;
    orow[c] = __float2bfloat16((v[i]-mu)*rs*scale[c] + bias[c]);
  }
}

__global__ __launch_bounds__(256) void ln_kernel(
    const float* __restrict__ x, const float* __restrict__ scale,
    const float* __restrict__ bias, bf16* __restrict__ out)
{
  ln_body(x, scale, bias, out, blockIdx.x);
}

// ------------- prep kernel: 4 weight transposes + ln1, one launch -------------
// bid < 6912: weight transpose-cast segments; bid >= 6912: ln1 row.
__global__ __launch_bounds__(256) void prep_kernel(
    const float* __restrict__ s0, const float* __restrict__ s1,
    const float* __restrict__ s2, const float* __restrict__ s3,
    bf16* __restrict__ d0, bf16* __restrict__ d1,
    bf16* __restrict__ d2, bf16* __restrict__ d3,
    const float* __restrict__ x, const float* __restrict__ ln1s,
    const float* __restrict__ ln1b, bf16* __restrict__ h1)
{
  int bid = blockIdx.x;
  if (bid >= 6912) {             // ---- ln1 ----
    ln_body(x, ln1s, ln1b, h1, bid - 6912);
    return;
  }
  const float* src; bf16* dst; int K, N, r;
  if (bid < 1728)      { src = s0; dst = d0; K = 768;  N = 2304; r = bid; }
  else if (bid < 2304) { src = s1; dst = d1; K = 768;  N = 768;  r = bid - 1728; }
  else if (bid < 4608) { src = s2; dst = d2; K = 768;  N = 3072; r = bid - 2304; }
  else                 { src = s3; dst = d3; K = 3072; N = 768;  r = bid - 4608; }
  int nbx = N >> 5;
  int bx = r % nbx, by = r / nbx;
  __shared__ float tile[32][33];
  int n0 = bx * 32, k0 = by * 32;
  int tx = threadIdx.x & 31, ty = threadIdx.x >> 5;   // ty 0..7
  for (int i = 0; i < 4; i++)
    tile[ty + i*8][tx] = src[(size_t)(k0 + ty + i*8)*N + n0 + tx];
  __syncthreads();
  for (int i = 0; i < 4; i++)
    dst[(size_t)(n0 + ty + i*8)*K + k0 + tx] = __float2bfloat16(tile[tx][ty + i*8]);
}

// ------------- V transpose: [BH][T][64] -> [BH][64][T] (bf16) -------------
__global__ __launch_bounds__(256) void vtrans_kernel(
    const bf16* __restrict__ src, bf16* __restrict__ dst)
{
  __shared__ bf16 tile[64][65];
  int bh = blockIdx.x >> 4, t0 = (blockIdx.x & 15) * 64;
  const bf16* s = src + ((size_t)bh * TT + t0) * 64;
  for (int i = 0; i < 16; i++) {
    int idx = threadIdx.x + i*256;
    tile[idx >> 6][idx & 63] = s[idx];
  }
  __syncthreads();
  bf16* o = dst + (size_t)bh * 64 * TT + t0;
  for (int i = 0; i < 16; i++) {
    int idx = threadIdx.x + i*256;
    int d = idx >> 6, t = idx & 63;
    o[(size_t)d * TT + t] = tile[t][d];
  }
}

// ------------- 128x128 GEMM: C[M,N] = A_bf16[M,K] * Bt_bf16[N,K]^T + bias -------------
// BK=32, 2-deep register prefetch (round-10 incumbent: best measured).
// BK=64 falsified (r11: write-side bank conflicts from 128B row stride;
// FC flat even accounting for them -> barrier amortization exhausted).
template<int EPI>
__global__ __launch_bounds__(256) void gemm_bt(
    const bf16* __restrict__ A, const bf16* __restrict__ Bt,
    const float* __restrict__ bias, int Mdim, int Ndim, int Kdim,
    const float* __restrict__ res, void* __restrict__ out0,
    bf16* __restrict__ outK, bf16* __restrict__ outV)
{
  __shared__ bf16 As[2][128*32];
  __shared__ bf16 Bs[2][128*32];
  int tid = threadIdx.x;
  int wave = tid >> 6, lane = tid & 63;
  int quad = lane >> 4, l15 = lane & 15;
  int wr = wave >> 1, wc = wave & 1;

  int Nb = gridDim.x;
  int lin = blockIdx.y * Nb + blockIdx.x;
  int band = lin / (8*Nb);
  int rem  = lin - band*8*Nb;
  int m0 = (band*8 + (rem & 7)) * 128;
  int n0 = (rem >> 3) * 128;

  const int sub = lane >> 2;       // 0..15
  const int kk = (lane & 3) * 8;

  f32x4 acc[4][4];
  for (int i = 0; i < 4; i++) for (int j = 0; j < 4; j++)
    acc[i][j] = (f32x4){0.f,0.f,0.f,0.f};

  const bf16* pa0 = A  + (size_t)(m0 + wave*16      + sub)*Kdim + kk;
  const bf16* pa1 = A  + (size_t)(m0 + (4+wave)*16  + sub)*Kdim + kk;
  const bf16* pb0 = Bt + (size_t)(n0 + wave*16      + sub)*Kdim + kk;
  const bf16* pb1 = Bt + (size_t)(n0 + (4+wave)*16  + sub)*Kdim + kk;
  const int wslot = (lane & 3) ^ ((lane >> 3) & 3);   // T2 swizzle (conflicts 0)
  const int woff0 = wave*512     + sub*32 + wslot*8;  // bf16 units
  const int woff1 = (4+wave)*512 + sub*32 + wslot*8;

  const int rsw = (quad ^ ((l15 >> 1) & 3)) * 8;

  const int niter = Kdim >> 5;     // even for all shapes here (24 or 96)
  const int nd = niter >> 1;

#define LOADSET(ra0_,ra1_,rb0_,rb1_) do { \
    ra0_ = *reinterpret_cast<const bf16x8*>(pa0); \
    ra1_ = *reinterpret_cast<const bf16x8*>(pa1); \
    rb0_ = *reinterpret_cast<const bf16x8*>(pb0); \
    rb1_ = *reinterpret_cast<const bf16x8*>(pb1); \
    pa0 += 32; pa1 += 32; pb0 += 32; pb1 += 32; } while(0)

#define WRITESET(buf,ra0_,ra1_,rb0_,rb1_) do { \
    *reinterpret_cast<bf16x8*>(As[buf] + woff0) = ra0_; \
    *reinterpret_cast<bf16x8*>(As[buf] + woff1) = ra1_; \
    *reinterpret_cast<bf16x8*>(Bs[buf] + woff0) = rb0_; \
    *reinterpret_cast<bf16x8*>(Bs[buf] + woff1) = rb1_; } while(0)

#define COMPUTE(buf) do { \
    bf16x8 bfr[4]; \
    for (int j = 0; j < 4; j++) \
      bfr[j] = *reinterpret_cast<const bf16x8*>(Bs[buf] + (wc*64 + j*16 + l15)*32 + rsw); \
    for (int i = 0; i < 4; i++) { \
      bf16x8 af = *reinterpret_cast<const bf16x8*>(As[buf] + (wr*64 + i*16 + l15)*32 + rsw); \
      for (int j = 0; j < 4; j++) \
        acc[i][j] = MFMA16(af, bfr[j], acc[i][j]); \
    } } while(0)

  // prologue: tiles 0 (set A) and 1 (set B) in flight; write tile 0 -> buf 0
  bf16x8 rAa0, rAa1, rAb0, rAb1;   // set A
  bf16x8 rBa0, rBa1, rBb0, rBb1;   // set B
  LOADSET(rAa0, rAa1, rAb0, rAb1);
  LOADSET(rBa0, rBa1, rBb0, rBb1);
  WRITESET(0, rAa0, rAa1, rAb0, rAb1);   // vmcnt wait covers set A only
  lds_barrier();

  for (int d = 0; d < nd; d++) {
    bool mA = (2*d + 2 < niter);
    bool mB = (2*d + 3 < niter);
    // set A was consumed into LDS last round -> reload with tile 2d+2
    if (mA) LOADSET(rAa0, rAa1, rAb0, rAb1);
    COMPUTE(0);                          // tile 2d
    // set B (tile 2d+1): loads issued one full iteration ago
    WRITESET(1, rBa0, rBa1, rBb0, rBb1);
    lds_barrier();
    if (mB) LOADSET(rBa0, rBa1, rBb0, rBb1);   // tile 2d+3
    COMPUTE(1);                          // tile 2d+1
    if (mA) {
      WRITESET(0, rAa0, rAa1, rAb0, rAb1);     // tile 2d+2
      lds_barrier();
    }
  }
#undef LOADSET
#undef WRITESET
#undef COMPUTE

  for (int i = 0; i < 4; i++) {
    for (int j = 0; j < 4; j++) {
      for (int r = 0; r < 4; r++) {
        int row = m0 + wr*64 + i*16 + quad*4 + r;
        int col = n0 + wc*64 + j*16 + l15;
        float cv = acc[i][j][r] + bias[col];
        if (EPI == 0) {
          int part = col / 768;
          int cc = col - part*768;
          int h = cc >> 6, d = cc & 63;
          int b = row >> 10, t = row & 1023;
          bf16* dst = (part == 0) ? (bf16*)out0 : (part == 1) ? outK : outV;
          dst[(((size_t)(b*HH + h))*TT + t)*64 + d] = __float2bfloat16(cv);
        } else if (EPI == 1) {
          ((float*)out0)[(size_t)row*Ndim + col] = cv + res[(size_t)row*Ndim + col];
        } else {
          float u = cv;
          float y = 0.7978845608f*(u + 0.044715f*u*u*u);
          float e = __expf(2.f*fabsf(y));
          float z = 2.f/(e + 1.f);                  // 1 - tanh(|y|)
          float sel = (y >= 0.f) ? (2.f - z) : z;   // 1 + tanh(y)
          ((bf16*)out0)[(size_t)row*Ndim + col] = __float2bfloat16(0.5f*u*sel);
        }
      }
    }
  }
}

// ------------- flash attention, QBLK=128, lgkm-only barriers -------------
// Barrier2 with __syncthreads drained the just-issued next-chunk K/V register
// prefetch (vmcnt(0)) before every compute phase. lgkm-only is legal here:
// outstanding vmem at both barriers = register-private loads; lgkmcnt(0)
// orders all LDS traffic. The compiler's vmcnt wait now lands at the NEXT
// chunk's ds_write -> prefetch overlaps the whole QK^T/softmax/PV phase.
__global__ __launch_bounds__(512) void attn_kernel(
    const bf16* __restrict__ Q, const bf16* __restrict__ Kb,
    const bf16* __restrict__ Vt, bf16* __restrict__ ctx)
{
  __shared__ bf16 Ks[64*64];      // [key][d], swizzled      (8 KB)
  __shared__ bf16 Vs[64*64];      // [d][key], swizzled      (8 KB)
  __shared__ bf16 Ps[8*16*64];    // per-wave [q][key], q-swizzled (16 KB)

  int tid = threadIdx.x, wave = tid >> 6, lane = tid & 63;
  int quad = lane >> 4, l15 = lane & 15;
  int bh = blockIdx.x >> 3;
  int tile = 7 - (blockIdx.x & 7);            // heavy tiles first
  int q0b = tile*128;
  int q0w = q0b + wave*16;
  int b = bh / HH, h = bh - b*HH;
  const bf16* Qp = Q + ((size_t)bh*TT + q0w)*64;
  const bf16* Kp = Kb + (size_t)bh*TT*64;
  const bf16* Vp = Vt + (size_t)bh*64*TT;
  bf16* Pw = Ps + wave*16*64;

  bf16x8 qf[2];
  qf[0] = *reinterpret_cast<const bf16x8*>(Qp + l15*64 + quad*8);
  qf[1] = *reinterpret_cast<const bf16x8*>(Qp + l15*64 + 32 + quad*8);

  f32x4 O[4];
  for (int j = 0; j < 4; j++) O[j] = (f32x4){0.f,0.f,0.f,0.f};
  float lsum[4] = {0.f, 0.f, 0.f, 0.f};
  const float c2 = 0.18033688f;   // (1/8) * log2(e)

  // staging: 512 threads cover 64 rows x 8 slots exactly (1 K + 1 V load each)
  const int srow = tid >> 3;      // 0..63
  const int sc   = tid & 7;       // 16B block within 128B row
  const int ph   = sc ^ (srow & 7);

  int nc = 2*tile + 2;            // number of 64-key chunks (covers q0b+127)

  bf16x8 kreg, vreg, kreg2, vreg2;
  kreg = *reinterpret_cast<const bf16x8*>(Kp + (size_t)srow*64 + sc*8);
  vreg = *reinterpret_cast<const bf16x8*>(Vp + (size_t)srow*TT + sc*8);

  for (int ci = 0; ci < nc; ci++) {
    int kbase = ci*64;
    lds_barrier();   // reads of previous chunk done; vmem prefetch stays live
    *reinterpret_cast<bf16x8*>(Ks + srow*64 + ph*8) = kreg;
    *reinterpret_cast<bf16x8*>(Vs + srow*64 + ph*8) = vreg;
    if (ci + 1 < nc) {
      int kb2 = kbase + 64;
      kreg2 = *reinterpret_cast<const bf16x8*>(Kp + (size_t)(kb2 + srow)*64 + sc*8);
      vreg2 = *reinterpret_cast<const bf16x8*>(Vp + (size_t)srow*TT + kb2 + sc*8);
    }
    lds_barrier();   // staged K/V visible; next-chunk loads remain in flight

    f32x4 S[4];
    for (int j = 0; j < 4; j++) S[j] = (f32x4){0.f,0.f,0.f,0.f};
    for (int kh = 0; kh < 2; kh++) {
      for (int j = 0; j < 4; j++) {
        int key = j*16 + l15;
        bf16x8 kf = *reinterpret_cast<const bf16x8*>(
            Ks + key*64 + ((kh*4 + quad) ^ (key & 7))*8);
        S[j] = MFMA16(qf[kh], kf, S[j]);
      }
    }

    float p[4][4];
    if (kbase + 63 > q0w) {
      for (int j = 0; j < 4; j++) {
        int key = kbase + j*16 + l15;
        for (int r = 0; r < 4; r++) {
          int row = q0w + quad*4 + r;
          p[j][r] = (key <= row) ? __builtin_amdgcn_exp2f(S[j][r]*c2) : 0.f;
        }
      }
    } else {
      for (int j = 0; j < 4; j++)
        for (int r = 0; r < 4; r++)
          p[j][r] = __builtin_amdgcn_exp2f(S[j][r]*c2);
    }
    for (int j = 0; j < 4; j++)
      for (int r = 0; r < 4; r++) lsum[r] += p[j][r];

    for (int j = 0; j < 4; j++) {
      int cblk = j*2 + (l15 >> 3);
      int koff = l15 & 7;
      for (int r = 0; r < 4; r++) {
        int q = quad*4 + r;
        Pw[q*64 + (cblk ^ (q & 7))*8 + koff] = __float2bfloat16(p[j][r]);
      }
    }

    for (int kh = 0; kh < 2; kh++) {
      bf16x8 pf = *reinterpret_cast<const bf16x8*>(
          Pw + l15*64 + ((kh*4 + quad) ^ (l15 & 7))*8);
      for (int j = 0; j < 4; j++) {
        int d = j*16 + l15;
        bf16x8 vf = *reinterpret_cast<const bf16x8*>(
            Vs + d*64 + ((kh*4 + quad) ^ (d & 7))*8);
        O[j] = MFMA16(pf, vf, O[j]);
      }
    }

    kreg = kreg2; vreg = vreg2;
  }

  for (int r = 0; r < 4; r++)
    for (int msk = 1; msk < 16; msk <<= 1)
      lsum[r] += __shfl_xor(lsum[r], msk);

  bf16* cp = ctx + ((size_t)b*TT + q0w)*CC + h*64;
  for (int r = 0; r < 4; r++) {
    float inv = 1.f / lsum[r];
    int row = quad*4 + r;
    for (int j = 0; j < 4; j++)
      cp[(size_t)row*CC + j*16 + l15] = __float2bfloat16(O[j][r]*inv);
  }
}

extern "C" void kernel_launch(void* const* d_in, const int* in_sizes, int n_in,
                              void* d_out, int out_size, void* d_ws, size_t ws_size,
                              hipStream_t stream)
{
  const float* x    = (const float*)d_in[0];
  const float* ln1s = (const float*)d_in[2];
  const float* ln1b = (const float*)d_in[3];
  const float* wqkv = (const float*)d_in[4];
  const float* bqkv = (const float*)d_in[5];
  const float* wap  = (const float*)d_in[6];
  const float* bap  = (const float*)d_in[7];
  const float* ln2s = (const float*)d_in[8];
  const float* ln2b = (const float*)d_in[9];
  const float* wfc  = (const float*)d_in[10];
  const float* bfc  = (const float*)d_in[11];
  const float* wmp  = (const float*)d_in[12];
  const float* bmp  = (const float*)d_in[13];

  char* ws = (char*)d_ws;
  bf16* wqkv_t = (bf16*)ws; ws += (size_t)2304*768*2;
  bf16* wap_t  = (bf16*)ws; ws += (size_t)768*768*2;
  bf16* wfc_t  = (bf16*)ws; ws += (size_t)3072*768*2;
  bf16* wmp_t  = (bf16*)ws; ws += (size_t)768*3072*2;
  bf16* buf1   = (bf16*)ws; ws += (size_t)MROWS*CC*2;   // h / ctx / h2
  bf16* Qb     = (bf16*)ws; ws += (size_t)MROWS*CC*2;
  bf16* Kbuf   = (bf16*)ws; ws += (size_t)MROWS*CC*2;
  bf16* Vb     = (bf16*)ws; ws += (size_t)MROWS*CC*2;
  bf16* Vt     = (bf16*)ws; ws += (size_t)MROWS*CC*2;
  bf16* g      = Qb;  // reuse Q/K/V/Vt region for [8192][3072] bf16
  float* r1    = (float*)ws; ws += (size_t)MROWS*CC*4;

  dim3 blk(256);
  prep_kernel<<<6912 + MROWS, blk, 0, stream>>>(
      wqkv, wap, wfc, wmp, wqkv_t, wap_t, wfc_t, wmp_t,
      x, ln1s, ln1b, buf1);
  gemm_bt<0><<<dim3(2304/128, MROWS/128), blk, 0, stream>>>(
      buf1, wqkv_t, bqkv, MROWS, 2304, 768, nullptr, (void*)Qb, Kbuf, Vb);
  vtrans_kernel<<<BB*HH*16, blk, 0, stream>>>(Vb, Vt);
  attn_kernel<<<BB*HH*8, dim3(512), 0, stream>>>(Qb, Kbuf, Vt, buf1);
  gemm_bt<1><<<dim3(768/128, MROWS/128), blk, 0, stream>>>(
      buf1, wap_t, bap, MROWS, 768, 768, x, (void*)r1, nullptr, nullptr);
  ln_kernel<<<MROWS, blk, 0, stream>>>(r1, ln2s, ln2b, buf1);
  gemm_bt<2><<<dim3(3072/128, MROWS/128), blk, 0, stream>>>(
      buf1, wfc_t, bfc, MROWS, 3072, 768, nullptr, (void*)g, nullptr, nullptr);
  gemm_bt<1><<<dim3(768/128, MROWS/128), blk, 0, stream>>>(
      g, wmp_t, bmp, MROWS, 768, 3072, r1, d_out, nullptr, nullptr);
}

// Round 13
// 351.575 us; speedup vs baseline: 1.0392x; 1.0083x over previous
//
#include <hip/hip_runtime.h>
#include <hip/hip_bf16.h>
#include <cstdint>
#include <math.h>

// Problem dims
#define BB 8
#define TT 1024
#define CC 768
#define HH 12
#define MROWS (BB*TT)   // 8192

typedef __hip_bfloat16 bf16;
typedef __attribute__((ext_vector_type(8))) __bf16 bf16x8;
typedef __attribute__((ext_vector_type(4))) float f32x4;

#define MFMA16(a,b,c) __builtin_amdgcn_mfma_f32_16x16x32_bf16(a,b,c,0,0,0)

// lgkm-only barrier: legal when the only outstanding vmem ops at the
// barrier are private register loads (not observable cross-thread). Avoids
// the compiler's s_waitcnt vmcnt(0) drain at __syncthreads.
__device__ __forceinline__ void lds_barrier() {
  asm volatile("s_waitcnt lgkmcnt(0)\n\ts_barrier" ::: "memory");
}

// ---------------- LayerNorm body: f32 [rows][768] -> bf16 ----------------
__device__ __forceinline__ void ln_body(
    const float* __restrict__ x, const float* __restrict__ scale,
    const float* __restrict__ bias, bf16* __restrict__ out, int row)
{
  const float* xr = x + (size_t)row * CC;
  float v[3];
  float s = 0.f, s2 = 0.f;
  for (int i = 0; i < 3; i++) {
    v[i] = xr[threadIdx.x + i*256];
    s += v[i]; s2 += v[i]*v[i];
  }
  for (int m = 1; m < 64; m <<= 1) { s += __shfl_xor(s, m); s2 += __shfl_xor(s2, m); }
  __shared__ float ssum[4], ssum2[4];
  int w = threadIdx.x >> 6;
  if ((threadIdx.x & 63) == 0) { ssum[w] = s; ssum2[w] = s2; }
  __syncthreads();
  s = ssum[0]+ssum[1]+ssum[2]+ssum[3];
  s2 = ssum2[0]+ssum2[1]+ssum2[2]+ssum2[3];
  float mu = s * (1.f/CC);
  float var = s2 * (1.f/CC) - mu*mu;
  float rs = rsqrtf(var + 1e-5f);
  bf16* orow = out + (size_t)row * CC;
  for (int i = 0; i < 3; i++) {
    int c = threadIdx.x + i*256;
    orow[c] = __float2bfloat16((v[i]-mu)*rs*scale[c] + bias[c]);
  }
}

__global__ __launch_bounds__(256) void ln_kernel(
    const float* __restrict__ x, const float* __restrict__ scale,
    const float* __restrict__ bias, bf16* __restrict__ out)
{
  ln_body(x, scale, bias, out, blockIdx.x);
}

// ------------- prep kernel: 4 weight transposes + ln1, one launch -------------
__global__ __launch_bounds__(256) void prep_kernel(
    const float* __restrict__ s0, const float* __restrict__ s1,
    const float* __restrict__ s2, const float* __restrict__ s3,
    bf16* __restrict__ d0, bf16* __restrict__ d1,
    bf16* __restrict__ d2, bf16* __restrict__ d3,
    const float* __restrict__ x, const float* __restrict__ ln1s,
    const float* __restrict__ ln1b, bf16* __restrict__ h1)
{
  int bid = blockIdx.x;
  if (bid >= 6912) {             // ---- ln1 ----
    ln_body(x, ln1s, ln1b, h1, bid - 6912);
    return;
  }
  const float* src; bf16* dst; int K, N, r;
  if (bid < 1728)      { src = s0; dst = d0; K = 768;  N = 2304; r = bid; }
  else if (bid < 2304) { src = s1; dst = d1; K = 768;  N = 768;  r = bid - 1728; }
  else if (bid < 4608) { src = s2; dst = d2; K = 768;  N = 3072; r = bid - 2304; }
  else                 { src = s3; dst = d3; K = 3072; N = 768;  r = bid - 4608; }
  int nbx = N >> 5;
  int bx = r % nbx, by = r / nbx;
  __shared__ float tile[32][33];
  int n0 = bx * 32, k0 = by * 32;
  int tx = threadIdx.x & 31, ty = threadIdx.x >> 5;   // ty 0..7
  for (int i = 0; i < 4; i++)
    tile[ty + i*8][tx] = src[(size_t)(k0 + ty + i*8)*N + n0 + tx];
  __syncthreads();
  for (int i = 0; i < 4; i++)
    dst[(size_t)(n0 + ty + i*8)*K + k0 + tx] = __float2bfloat16(tile[tx][ty + i*8]);
}

// ------------- V transpose: [BH][T][64] -> [BH][64][T] (bf16) -------------
__global__ __launch_bounds__(256) void vtrans_kernel(
    const bf16* __restrict__ src, bf16* __restrict__ dst)
{
  __shared__ bf16 tile[64][65];
  int bh = blockIdx.x >> 4, t0 = (blockIdx.x & 15) * 64;
  const bf16* s = src + ((size_t)bh * TT + t0) * 64;
  for (int i = 0; i < 16; i++) {
    int idx = threadIdx.x + i*256;
    tile[idx >> 6][idx & 63] = s[idx];
  }
  __syncthreads();
  bf16* o = dst + (size_t)bh * 64 * TT + t0;
  for (int i = 0; i < 16; i++) {
    int idx = threadIdx.x + i*256;
    int d = idx >> 6, t = idx & 63;
    o[(size_t)d * TT + t] = tile[t][d];
  }
}

// ------------- 128x128 GEMM: C[M,N] = A_bf16[M,K] * Bt_bf16[N,K]^T + bias -------------
// BK=32, 2-deep register prefetch (round-10 incumbent: best measured).
template<int EPI>
__global__ __launch_bounds__(256) void gemm_bt(
    const bf16* __restrict__ A, const bf16* __restrict__ Bt,
    const float* __restrict__ bias, int Mdim, int Ndim, int Kdim,
    const float* __restrict__ res, void* __restrict__ out0,
    bf16* __restrict__ outK, bf16* __restrict__ outV)
{
  __shared__ bf16 As[2][128*32];
  __shared__ bf16 Bs[2][128*32];
  int tid = threadIdx.x;
  int wave = tid >> 6, lane = tid & 63;
  int quad = lane >> 4, l15 = lane & 15;
  int wr = wave >> 1, wc = wave & 1;

  int Nb = gridDim.x;
  int lin = blockIdx.y * Nb + blockIdx.x;
  int band = lin / (8*Nb);
  int rem  = lin - band*8*Nb;
  int m0 = (band*8 + (rem & 7)) * 128;
  int n0 = (rem >> 3) * 128;

  const int sub = lane >> 2;       // 0..15
  const int kk = (lane & 3) * 8;

  f32x4 acc[4][4];
  for (int i = 0; i < 4; i++) for (int j = 0; j < 4; j++)
    acc[i][j] = (f32x4){0.f,0.f,0.f,0.f};

  const bf16* pa0 = A  + (size_t)(m0 + wave*16      + sub)*Kdim + kk;
  const bf16* pa1 = A  + (size_t)(m0 + (4+wave)*16  + sub)*Kdim + kk;
  const bf16* pb0 = Bt + (size_t)(n0 + wave*16      + sub)*Kdim + kk;
  const bf16* pb1 = Bt + (size_t)(n0 + (4+wave)*16  + sub)*Kdim + kk;
  const int wslot = (lane & 3) ^ ((lane >> 3) & 3);   // T2 swizzle (conflicts 0)
  const int woff0 = wave*512     + sub*32 + wslot*8;  // bf16 units
  const int woff1 = (4+wave)*512 + sub*32 + wslot*8;

  const int rsw = (quad ^ ((l15 >> 1) & 3)) * 8;

  const int niter = Kdim >> 5;     // even for all shapes here (24 or 96)
  const int nd = niter >> 1;

#define LOADSET(ra0_,ra1_,rb0_,rb1_) do { \
    ra0_ = *reinterpret_cast<const bf16x8*>(pa0); \
    ra1_ = *reinterpret_cast<const bf16x8*>(pa1); \
    rb0_ = *reinterpret_cast<const bf16x8*>(pb0); \
    rb1_ = *reinterpret_cast<const bf16x8*>(pb1); \
    pa0 += 32; pa1 += 32; pb0 += 32; pb1 += 32; } while(0)

#define WRITESET(buf,ra0_,ra1_,rb0_,rb1_) do { \
    *reinterpret_cast<bf16x8*>(As[buf] + woff0) = ra0_; \
    *reinterpret_cast<bf16x8*>(As[buf] + woff1) = ra1_; \
    *reinterpret_cast<bf16x8*>(Bs[buf] + woff0) = rb0_; \
    *reinterpret_cast<bf16x8*>(Bs[buf] + woff1) = rb1_; } while(0)

#define COMPUTE(buf) do { \
    bf16x8 bfr[4]; \
    for (int j = 0; j < 4; j++) \
      bfr[j] = *reinterpret_cast<const bf16x8*>(Bs[buf] + (wc*64 + j*16 + l15)*32 + rsw); \
    for (int i = 0; i < 4; i++) { \
      bf16x8 af = *reinterpret_cast<const bf16x8*>(As[buf] + (wr*64 + i*16 + l15)*32 + rsw); \
      for (int j = 0; j < 4; j++) \
        acc[i][j] = MFMA16(af, bfr[j], acc[i][j]); \
    } } while(0)

  // prologue: tiles 0 (set A) and 1 (set B) in flight; write tile 0 -> buf 0
  bf16x8 rAa0, rAa1, rAb0, rAb1;   // set A
  bf16x8 rBa0, rBa1, rBb0, rBb1;   // set B
  LOADSET(rAa0, rAa1, rAb0, rAb1);
  LOADSET(rBa0, rBa1, rBb0, rBb1);
  WRITESET(0, rAa0, rAa1, rAb0, rAb1);   // vmcnt wait covers set A only
  lds_barrier();

  for (int d = 0; d < nd; d++) {
    bool mA = (2*d + 2 < niter);
    bool mB = (2*d + 3 < niter);
    // set A was consumed into LDS last round -> reload with tile 2d+2
    if (mA) LOADSET(rAa0, rAa1, rAb0, rAb1);
    COMPUTE(0);                          // tile 2d
    // set B (tile 2d+1): loads issued one full iteration ago
    WRITESET(1, rBa0, rBa1, rBb0, rBb1);
    lds_barrier();
    if (mB) LOADSET(rBa0, rBa1, rBb0, rBb1);   // tile 2d+3
    COMPUTE(1);                          // tile 2d+1
    if (mA) {
      WRITESET(0, rAa0, rAa1, rAb0, rAb1);     // tile 2d+2
      lds_barrier();
    }
  }
#undef LOADSET
#undef WRITESET
#undef COMPUTE

  for (int i = 0; i < 4; i++) {
    for (int j = 0; j < 4; j++) {
      for (int r = 0; r < 4; r++) {
        int row = m0 + wr*64 + i*16 + quad*4 + r;
        int col = n0 + wc*64 + j*16 + l15;
        float cv = acc[i][j][r] + bias[col];
        if (EPI == 0) {
          int part = col / 768;
          int cc = col - part*768;
          int h = cc >> 6, d = cc & 63;
          int b = row >> 10, t = row & 1023;
          bf16* dst = (part == 0) ? (bf16*)out0 : (part == 1) ? outK : outV;
          dst[(((size_t)(b*HH + h))*TT + t)*64 + d] = __float2bfloat16(cv);
        } else if (EPI == 1) {
          ((float*)out0)[(size_t)row*Ndim + col] = cv + res[(size_t)row*Ndim + col];
        } else {
          float u = cv;
          float y = 0.7978845608f*(u + 0.044715f*u*u*u);
          float e = __expf(2.f*fabsf(y));
          float z = 2.f/(e + 1.f);                  // 1 - tanh(|y|)
          float sel = (y >= 0.f) ? (2.f - z) : z;   // 1 + tanh(y)
          ((bf16*)out0)[(size_t)row*Ndim + col] = __float2bfloat16(0.5f*u*sel);
        }
      }
    }
  }
}

// ------------- flash attention, QBLK=128, double-buffered K/V, 1 barrier/chunk ----
// Dbuf removes the mid-chunk barrier: iter ci writes buf[nxt] (regs preloaded
// a full phase earlier), computes from buf[cur], then one lgkm barrier.
// Hazards: reads of buf[nxt] finished before iter ci-1's closing barrier
// (safe to overwrite); writes of buf[nxt] drain at iter ci's closing
// lgkmcnt(0) barrier (visible for ci+1). Global prefetch is 2 chunks ahead.
__global__ __launch_bounds__(512) void attn_kernel(
    const bf16* __restrict__ Q, const bf16* __restrict__ Kb,
    const bf16* __restrict__ Vt, bf16* __restrict__ ctx)
{
  __shared__ bf16 Ks[2][64*64];   // [key][d], swizzled      (16 KB)
  __shared__ bf16 Vs[2][64*64];   // [d][key], swizzled      (16 KB)
  __shared__ bf16 Ps[8*16*64];    // per-wave [q][key], q-swizzled (16 KB)

  int tid = threadIdx.x, wave = tid >> 6, lane = tid & 63;
  int quad = lane >> 4, l15 = lane & 15;
  int bh = blockIdx.x >> 3;
  int tile = 7 - (blockIdx.x & 7);            // heavy tiles first
  int q0b = tile*128;
  int q0w = q0b + wave*16;
  int b = bh / HH, h = bh - b*HH;
  const bf16* Qp = Q + ((size_t)bh*TT + q0w)*64;
  const bf16* Kp = Kb + (size_t)bh*TT*64;
  const bf16* Vp = Vt + (size_t)bh*64*TT;
  bf16* Pw = Ps + wave*16*64;

  bf16x8 qf[2];
  qf[0] = *reinterpret_cast<const bf16x8*>(Qp + l15*64 + quad*8);
  qf[1] = *reinterpret_cast<const bf16x8*>(Qp + l15*64 + 32 + quad*8);

  f32x4 O[4];
  for (int j = 0; j < 4; j++) O[j] = (f32x4){0.f,0.f,0.f,0.f};
  float lsum[4] = {0.f, 0.f, 0.f, 0.f};
  const float c2 = 0.18033688f;   // (1/8) * log2(e)

  // staging: 512 threads cover 64 rows x 8 slots exactly (1 K + 1 V load each)
  const int srow = tid >> 3;      // 0..63
  const int sc   = tid & 7;       // 16B block within 128B row
  const int ph   = sc ^ (srow & 7);
  const int wofK = srow*64 + ph*8;

  int nc = 2*tile + 2;            // number of 64-key chunks (covers q0b+127)

  // prologue: stage chunk 0 into buf 0; preload chunk 1 into regs
  bf16x8 kw, vw;
  kw = *reinterpret_cast<const bf16x8*>(Kp + (size_t)srow*64 + sc*8);
  vw = *reinterpret_cast<const bf16x8*>(Vp + (size_t)srow*TT + sc*8);
  *reinterpret_cast<bf16x8*>(Ks[0] + wofK) = kw;
  *reinterpret_cast<bf16x8*>(Vs[0] + wofK) = vw;
  if (nc > 1) {
    kw = *reinterpret_cast<const bf16x8*>(Kp + (size_t)(64 + srow)*64 + sc*8);
    vw = *reinterpret_cast<const bf16x8*>(Vp + (size_t)srow*TT + 64 + sc*8);
  }
  lds_barrier();

  for (int ci = 0; ci < nc; ci++) {
    int cur = ci & 1, nxt = cur ^ 1;
    int kbase = ci*64;
    if (ci + 1 < nc) {           // stage chunk ci+1 (regs loaded a phase ago)
      *reinterpret_cast<bf16x8*>(Ks[nxt] + wofK) = kw;
      *reinterpret_cast<bf16x8*>(Vs[nxt] + wofK) = vw;
    }
    if (ci + 2 < nc) {           // prefetch chunk ci+2 (2 phases of cover)
      int kb2 = kbase + 128;
      kw = *reinterpret_cast<const bf16x8*>(Kp + (size_t)(kb2 + srow)*64 + sc*8);
      vw = *reinterpret_cast<const bf16x8*>(Vp + (size_t)srow*TT + kb2 + sc*8);
    }

    f32x4 S[4];
    for (int j = 0; j < 4; j++) S[j] = (f32x4){0.f,0.f,0.f,0.f};
    for (int kh = 0; kh < 2; kh++) {
      for (int j = 0; j < 4; j++) {
        int key = j*16 + l15;
        bf16x8 kf = *reinterpret_cast<const bf16x8*>(
            Ks[cur] + key*64 + ((kh*4 + quad) ^ (key & 7))*8);
        S[j] = MFMA16(qf[kh], kf, S[j]);
      }
    }

    float p[4][4];
    if (kbase + 63 > q0w) {
      for (int j = 0; j < 4; j++) {
        int key = kbase + j*16 + l15;
        for (int r = 0; r < 4; r++) {
          int row = q0w + quad*4 + r;
          p[j][r] = (key <= row) ? __builtin_amdgcn_exp2f(S[j][r]*c2) : 0.f;
        }
      }
    } else {
      for (int j = 0; j < 4; j++)
        for (int r = 0; r < 4; r++)
          p[j][r] = __builtin_amdgcn_exp2f(S[j][r]*c2);
    }
    for (int j = 0; j < 4; j++)
      for (int r = 0; r < 4; r++) lsum[r] += p[j][r];

    for (int j = 0; j < 4; j++) {
      int cblk = j*2 + (l15 >> 3);
      int koff = l15 & 7;
      for (int r = 0; r < 4; r++) {
        int q = quad*4 + r;
        Pw[q*64 + (cblk ^ (q & 7))*8 + koff] = __float2bfloat16(p[j][r]);
      }
    }

    for (int kh = 0; kh < 2; kh++) {
      bf16x8 pf = *reinterpret_cast<const bf16x8*>(
          Pw + l15*64 + ((kh*4 + quad) ^ (l15 & 7))*8);
      for (int j = 0; j < 4; j++) {
        int d = j*16 + l15;
        bf16x8 vf = *reinterpret_cast<const bf16x8*>(
            Vs[cur] + d*64 + ((kh*4 + quad) ^ (d & 7))*8);
        O[j] = MFMA16(pf, vf, O[j]);
      }
    }

    if (ci + 1 < nc) lds_barrier();   // reads of cur done; nxt staged & visible
  }

  for (int r = 0; r < 4; r++)
    for (int msk = 1; msk < 16; msk <<= 1)
      lsum[r] += __shfl_xor(lsum[r], msk);

  bf16* cp = ctx + ((size_t)b*TT + q0w)*CC + h*64;
  for (int r = 0; r < 4; r++) {
    float inv = 1.f / lsum[r];
    int row = quad*4 + r;
    for (int j = 0; j < 4; j++)
      cp[(size_t)row*CC + j*16 + l15] = __float2bfloat16(O[j][r]*inv);
  }
}

extern "C" void kernel_launch(void* const* d_in, const int* in_sizes, int n_in,
                              void* d_out, int out_size, void* d_ws, size_t ws_size,
                              hipStream_t stream)
{
  const float* x    = (const float*)d_in[0];
  const float* ln1s = (const float*)d_in[2];
  const float* ln1b = (const float*)d_in[3];
  const float* wqkv = (const float*)d_in[4];
  const float* bqkv = (const float*)d_in[5];
  const float* wap  = (const float*)d_in[6];
  const float* bap  = (const float*)d_in[7];
  const float* ln2s = (const float*)d_in[8];
  const float* ln2b = (const float*)d_in[9];
  const float* wfc  = (const float*)d_in[10];
  const float* bfc  = (const float*)d_in[11];
  const float* wmp  = (const float*)d_in[12];
  const float* bmp  = (const float*)d_in[13];

  char* ws = (char*)d_ws;
  bf16* wqkv_t = (bf16*)ws; ws += (size_t)2304*768*2;
  bf16* wap_t  = (bf16*)ws; ws += (size_t)768*768*2;
  bf16* wfc_t  = (bf16*)ws; ws += (size_t)3072*768*2;
  bf16* wmp_t  = (bf16*)ws; ws += (size_t)768*3072*2;
  bf16* buf1   = (bf16*)ws; ws += (size_t)MROWS*CC*2;   // h / ctx / h2
  bf16* Qb     = (bf16*)ws; ws += (size_t)MROWS*CC*2;
  bf16* Kbuf   = (bf16*)ws; ws += (size_t)MROWS*CC*2;
  bf16* Vb     = (bf16*)ws; ws += (size_t)MROWS*CC*2;
  bf16* Vt     = (bf16*)ws; ws += (size_t)MROWS*CC*2;
  bf16* g      = Qb;  // reuse Q/K/V/Vt region for [8192][3072] bf16
  float* r1    = (float*)ws; ws += (size_t)MROWS*CC*4;

  dim3 blk(256);
  prep_kernel<<<6912 + MROWS, blk, 0, stream>>>(
      wqkv, wap, wfc, wmp, wqkv_t, wap_t, wfc_t, wmp_t,
      x, ln1s, ln1b, buf1);
  gemm_bt<0><<<dim3(2304/128, MROWS/128), blk, 0, stream>>>(
      buf1, wqkv_t, bqkv, MROWS, 2304, 768, nullptr, (void*)Qb, Kbuf, Vb);
  vtrans_kernel<<<BB*HH*16, blk, 0, stream>>>(Vb, Vt);
  attn_kernel<<<BB*HH*8, dim3(512), 0, stream>>>(Qb, Kbuf, Vt, buf1);
  gemm_bt<1><<<dim3(768/128, MROWS/128), blk, 0, stream>>>(
      buf1, wap_t, bap, MROWS, 768, 768, x, (void*)r1, nullptr, nullptr);
  ln_kernel<<<MROWS, blk, 0, stream>>>(r1, ln2s, ln2b, buf1);
  gemm_bt<2><<<dim3(3072/128, MROWS/128), blk, 0, stream>>>(
      buf1, wfc_t, bfc, MROWS, 3072, 768, nullptr, (void*)g, nullptr, nullptr);
  gemm_bt<1><<<dim3(768/128, MROWS/128), blk, 0, stream>>>(
      g, wmp_t, bmp, MROWS, 768, 3072, r1, d_out, nullptr, nullptr);
}